// Round 3
// baseline (1126.980 us; speedup 1.0000x reference)
//
#include <hip/hip_runtime.h>
#include <hip/hip_bf16.h>

#define CDIM 256
#define MDIM 196
#define MATN (CDIM*CDIM)          // 65536
#define DTRI (CDIM*(CDIM+1)/2)    // 32896
#define PLANE 65536               // elements per bf16 plane
#define SLOT_STRIDE (2*PLANE)     // ushorts per batch per matrix slot (hi + lo plane)

typedef __attribute__((ext_vector_type(8))) short bf16x8;
typedef __attribute__((ext_vector_type(4))) float f32x4;

__device__ __constant__ int UTI[10] = {0,0,0,0,1,1,1,2,2,3};
__device__ __constant__ int UTJ[10] = {0,1,2,3,1,2,3,2,3,3};

__device__ __forceinline__ unsigned short f2bf(float f) {
    unsigned int u = __builtin_bit_cast(unsigned int, f);
    u = u + 0x7fff + ((u >> 16) & 1);           // RNE
    return (unsigned short)(u >> 16);
}
__device__ __forceinline__ float bf2f(unsigned short h) {
    unsigned int u = ((unsigned int)h) << 16;
    return __builtin_bit_cast(float, u);
}

// ---------- x -> bf16 hi/lo planes (K padded 196->256 with zeros) + row means + norm zero ----------
__global__ __launch_bounds__(256) void xcast_kernel(const float* __restrict__ x,
        unsigned short* __restrict__ xs, float* __restrict__ means, float* __restrict__ norm) {
    int b = blockIdx.y;
    int r0 = blockIdx.x * 64;
    int w = threadIdx.x >> 6, lane = threadIdx.x & 63;
    const float* xb = x + (size_t)b * CDIM * MDIM;
    unsigned short* xh = xs + (size_t)b * SLOT_STRIDE;
    unsigned short* xl = xh + PLANE;
    if (threadIdx.x == 0 && blockIdx.x == 0) norm[b] = 0.f;
    for (int k = 0; k < 16; k++) {
        int row = r0 + w * 16 + k;
        float v[4];
        float s = 0.f;
#pragma unroll
        for (int j = 0; j < 4; j++) {
            int c = j * 64 + lane;
            v[j] = (c < MDIM) ? xb[row * MDIM + c] : 0.f;
            s += v[j];
        }
#pragma unroll
        for (int off = 32; off > 0; off >>= 1) s += __shfl_down(s, off);
        if (lane == 0) means[b * CDIM + row] = s * (1.f / MDIM);
#pragma unroll
        for (int j = 0; j < 4; j++) {
            int c = j * 64 + lane;
            unsigned short h = f2bf(v[j]);
            xh[row * CDIM + c] = h;
            xl[row * CDIM + c] = f2bf(v[j] - bf2f(h));
        }
    }
}

// ---------- Ahat = A/norm (in place), Z0 = 1.5 I - 0.5 Ahat ----------
__global__ void prep_kernel(unsigned short* __restrict__ A, unsigned short* __restrict__ Z,
                            const float* __restrict__ norm, int bc) {
    int idx = blockIdx.x * 256 + threadIdx.x;   // one thread per 8 elements
    int total = bc * (MATN / 8);
    if (idx >= total) return;
    int b = idx >> 13;                          // MATN/8 = 8192
    int e0 = (idx & 8191) << 3;
    int r = e0 >> 8, c0 = e0 & 255;
    unsigned short* Ahi = A + (size_t)b * SLOT_STRIDE;
    unsigned short* Alo = Ahi + PLANE;
    unsigned short* Zhi = Z + (size_t)b * SLOT_STRIDE;
    unsigned short* Zlo = Zhi + PLANE;
    float inv = 1.f / norm[b];
    unsigned short h[8], l[8], ah[8], al[8], zh[8], zl[8];
    *(uint4*)h = *(const uint4*)&Ahi[e0];
    *(uint4*)l = *(const uint4*)&Alo[e0];
#pragma unroll
    for (int k = 0; k < 8; k++) {
        float val = (bf2f(h[k]) + bf2f(l[k])) * inv;        // Ahat element
        unsigned short hh = f2bf(val);
        ah[k] = hh; al[k] = f2bf(val - bf2f(hh));
        float z = ((r == c0 + k) ? 1.5f : 0.f) - 0.5f * val;
        unsigned short zz = f2bf(z);
        zh[k] = zz; zl[k] = f2bf(z - bf2f(zz));
    }
    *(uint4*)&Ahi[e0] = *(uint4*)ah;
    *(uint4*)&Alo[e0] = *(uint4*)al;
    *(uint4*)&Zhi[e0] = *(uint4*)zh;
    *(uint4*)&Zlo[e0] = *(uint4*)zl;
}

// ---------- unified batched MFMA GEMM on hi/lo bf16 planes, symmetric-output (upper tiles only) ----
// kind 0: D = A@B/M - mu mu^T (covariance), fused trace->atomicAdd(norm)
// kind 1: D = alpha*A@B + beta*C
// kind 2: fc epilogue: out[b0+b] += fc(triu(sqrt(norm)*(alpha*A@B + beta*C)))  (no D write)
// Grid: (10, bc). Tile (i,j), i<=j; i<j tiles also write the mirrored block (outputs symmetric).
__global__ __launch_bounds__(256) void bgemm_kernel(
        const unsigned short* __restrict__ Abase, const unsigned short* __restrict__ Bbase,
        const unsigned short* __restrict__ Cbase, unsigned short* __restrict__ Dbase,
        float alpha, float beta, int kind, float* __restrict__ norm,
        const float* __restrict__ means,
        const float* __restrict__ fcw, float* __restrict__ out, int b0) {
    __shared__ __align__(16) char lds[2][4][8192];   // [dbuf][Ah,Al,Bh,Bl][64 rows x 8 chunks x 16B]
    int tid = threadIdx.x;
    int b = blockIdx.y;
    int ti = UTI[blockIdx.x], tj = UTJ[blockIdx.x];
    int r0 = ti * 64, c0 = tj * 64;

    const unsigned short* Ab = Abase + (size_t)b * SLOT_STRIDE;
    const unsigned short* Bb = Bbase + (size_t)b * SLOT_STRIDE;
    const unsigned short* srcs[4] = { Ab + (size_t)r0 * CDIM, Ab + PLANE + (size_t)r0 * CDIM,
                                      Bb + (size_t)c0 * CDIM, Bb + PLANE + (size_t)c0 * CDIM };

    int w = tid >> 6, lane = tid & 63;
    int wr = w >> 1, wc = w & 1;
    int fr = lane & 15, kq = lane >> 4;

    f32x4 acc[2][2];
#pragma unroll
    for (int i = 0; i < 2; i++)
#pragma unroll
        for (int j = 0; j < 2; j++) acc[i][j] = (f32x4){0.f, 0.f, 0.f, 0.f};

    // LDS chunk (m, c) holds logical k-window (c ^ (m&7)); dest is wave-linear so
    // global_load_lds works; the swizzle lives in the per-lane GLOBAL address.
#define STAGE(buf, k0) do {                                                              \
    _Pragma("unroll")                                                                    \
    for (int p = 0; p < 4; p++) {                                                        \
        _Pragma("unroll")                                                                \
        for (int s = 0; s < 2; s++) {                                                    \
            int cid = s * 256 + tid;                                                     \
            int m = cid >> 3;                                                            \
            int kg = (cid & 7) ^ (m & 7);                                                \
            const unsigned short* g = srcs[p] + (size_t)m * CDIM + (k0) + kg * 8;        \
            void* lp = (void*)&lds[buf][p][(s * 256 + (tid & ~63)) * 16];                \
            __builtin_amdgcn_global_load_lds(                                            \
                (const __attribute__((address_space(1))) void*)g,                        \
                (__attribute__((address_space(3))) void*)(unsigned int)(unsigned long long)lp, \
                16, 0, 0);                                                               \
        }                                                                                \
    } } while (0)

    STAGE(0, 0);
    __syncthreads();

    int cur = 0;
    for (int k0 = 0; k0 < CDIM; k0 += 64) {
        if (k0 + 64 < CDIM) STAGE(cur ^ 1, k0 + 64);
#pragma unroll
        for (int h = 0; h < 2; h++) {
            bf16x8 fAh[2], fAl[2], fBh[2], fBl[2];
#pragma unroll
            for (int i = 0; i < 2; i++) {
                int mL = wr * 32 + i * 16 + fr;
                int ca = ((h * 4 + kq) ^ (mL & 7));
                fAh[i] = *(const bf16x8*)&lds[cur][0][(mL * 8 + ca) * 16];
                fAl[i] = *(const bf16x8*)&lds[cur][1][(mL * 8 + ca) * 16];
                int nL = wc * 32 + i * 16 + fr;
                int cb = ((h * 4 + kq) ^ (nL & 7));
                fBh[i] = *(const bf16x8*)&lds[cur][2][(nL * 8 + cb) * 16];
                fBl[i] = *(const bf16x8*)&lds[cur][3][(nL * 8 + cb) * 16];
            }
#pragma unroll
            for (int i = 0; i < 2; i++)
#pragma unroll
                for (int j = 0; j < 2; j++) {
                    acc[i][j] = __builtin_amdgcn_mfma_f32_16x16x32_bf16(fAh[i], fBh[j], acc[i][j], 0, 0, 0);
                    acc[i][j] = __builtin_amdgcn_mfma_f32_16x16x32_bf16(fAh[i], fBl[j], acc[i][j], 0, 0, 0);
                    acc[i][j] = __builtin_amdgcn_mfma_f32_16x16x32_bf16(fAl[i], fBh[j], acc[i][j], 0, 0, 0);
                }
        }
        __syncthreads();
        cur ^= 1;
    }

    const unsigned short* Chi = Cbase ? Cbase + (size_t)b * SLOT_STRIDE : nullptr;
    const unsigned short* Clo = Chi ? Chi + PLANE : nullptr;

    if (kind == 2) {
        float s = sqrtf(norm[b]);
        float s0 = 0.f, s1 = 0.f;
#pragma unroll
        for (int i = 0; i < 2; i++)
#pragma unroll
            for (int j = 0; j < 2; j++)
#pragma unroll
                for (int rr = 0; rr < 4; rr++) {
                    int row = r0 + wr * 32 + i * 16 + kq * 4 + rr;
                    int col = c0 + wc * 32 + j * 16 + fr;
                    float v = alpha * acc[i][j][rr];
                    if (Chi) v += beta * (bf2f(Chi[row * CDIM + col]) + bf2f(Clo[row * CDIM + col]));
                    v *= s;
                    if (col >= row) {
                        int t = row * CDIM - (row * (row - 1)) / 2 + (col - row);
                        s0 = fmaf(v, fcw[t], s0);
                        s1 = fmaf(v, fcw[DTRI + t], s1);
                    }
                }
#pragma unroll
        for (int off = 32; off > 0; off >>= 1) { s0 += __shfl_down(s0, off); s1 += __shfl_down(s1, off); }
        __syncthreads();
        float* red = (float*)&lds[0][0][0];
        if (lane == 0) { red[w * 2] = s0; red[w * 2 + 1] = s1; }
        __syncthreads();
        if (tid == 0) {
            atomicAdd(&out[(size_t)(b0 + b) * 2 + 0], red[0] + red[2] + red[4] + red[6]);
            atomicAdd(&out[(size_t)(b0 + b) * 2 + 1], red[1] + red[3] + red[5] + red[7]);
        }
        return;
    }

    // kind 0/1: compute values, direct write, then mirrored write for off-diagonal tiles
    float vv[2][2][4];
    if (kind == 0) {
        const float* mub = means + b * CDIM;
#pragma unroll
        for (int i = 0; i < 2; i++)
#pragma unroll
            for (int j = 0; j < 2; j++)
#pragma unroll
                for (int rr = 0; rr < 4; rr++) {
                    int row = r0 + wr * 32 + i * 16 + kq * 4 + rr;
                    int col = c0 + wc * 32 + j * 16 + fr;
                    float v = acc[i][j][rr] * (1.f / MDIM) - mub[row] * mub[col];
                    vv[i][j][rr] = v;
                    if (row == col) atomicAdd(&norm[b], v);   // fused trace
                }
    } else {
#pragma unroll
        for (int i = 0; i < 2; i++)
#pragma unroll
            for (int j = 0; j < 2; j++)
#pragma unroll
                for (int rr = 0; rr < 4; rr++) {
                    int row = r0 + wr * 32 + i * 16 + kq * 4 + rr;
                    int col = c0 + wc * 32 + j * 16 + fr;
                    float v = alpha * acc[i][j][rr];
                    if (Chi) v += beta * (bf2f(Chi[row * CDIM + col]) + bf2f(Clo[row * CDIM + col]));
                    vv[i][j][rr] = v;
                }
    }

    unsigned short* Dhi = Dbase + (size_t)b * SLOT_STRIDE;
    unsigned short* Dlo = Dhi + PLANE;
#pragma unroll
    for (int i = 0; i < 2; i++)
#pragma unroll
        for (int j = 0; j < 2; j++)
#pragma unroll
            for (int rr = 0; rr < 4; rr++) {
                int row = r0 + wr * 32 + i * 16 + kq * 4 + rr;
                int col = c0 + wc * 32 + j * 16 + fr;
                float v = vv[i][j][rr];
                unsigned short hh = f2bf(v);
                Dhi[row * CDIM + col] = hh;
                Dlo[row * CDIM + col] = f2bf(v - bf2f(hh));
            }

    if (ti != tj) {                              // mirrored block via padded LDS transpose
        float* T = (float*)&lds[0][0][0];        // [64][68] floats = 17408 B (fits in 64 KB)
#pragma unroll
        for (int i = 0; i < 2; i++)
#pragma unroll
            for (int j = 0; j < 2; j++)
#pragma unroll
                for (int rr = 0; rr < 4; rr++) {
                    int rl = wr * 32 + i * 16 + kq * 4 + rr;
                    int cl = wc * 32 + j * 16 + fr;
                    T[cl * 68 + rl] = vv[i][j][rr];
                }
        __syncthreads();
#pragma unroll
        for (int t = 0; t < 16; t++) {
            int idx = t * 256 + tid;
            int rr_ = idx >> 6;                  // local col index -> mirrored row
            int cc_ = idx & 63;                  // local row index -> mirrored col
            float v = T[rr_ * 68 + cc_];
            unsigned short hh = f2bf(v);
            Dhi[(c0 + rr_) * CDIM + (r0 + cc_)] = hh;
            Dlo[(c0 + rr_) * CDIM + (r0 + cc_)] = f2bf(v - bf2f(hh));
        }
    }
#undef STAGE
}

// ---------- out init with bias ----------
__global__ void init_out(float* __restrict__ out, const float* __restrict__ bias, int n) {
    int i = blockIdx.x * 256 + threadIdx.x;
    if (i < n) out[i] = bias[i & 1];
}

extern "C" void kernel_launch(void* const* d_in, const int* in_sizes, int n_in,
                              void* d_out, int out_size, void* d_ws, size_t ws_size,
                              hipStream_t stream) {
    const float* x    = (const float*)d_in[0];
    const float* fc_w = (const float*)d_in[1];
    const float* fc_b = (const float*)d_in[2];
    float* out = (float*)d_out;
    int B = in_sizes[0] / (CDIM * MDIM);

    size_t per_b = (size_t)4 * SLOT_STRIDE * sizeof(unsigned short)
                 + (size_t)CDIM * sizeof(float) + sizeof(float);
    int Bcmax = (int)(ws_size / per_b);
    if (Bcmax < 1) Bcmax = 1;
    if (Bcmax > B) Bcmax = B;
    int nch = (B + Bcmax - 1) / Bcmax;
    int Bc = (B + nch - 1) / nch;                // balanced chunks

    char* p = (char*)d_ws;
    unsigned short* slot[4];
    for (int i = 0; i < 4; i++) { slot[i] = (unsigned short*)p; p += (size_t)Bc * SLOT_STRIDE * sizeof(unsigned short); }
    float* means = (float*)p; p += (size_t)Bc * CDIM * sizeof(float);
    float* norm  = (float*)p;

    init_out<<<(out_size + 255) / 256, 256, 0, stream>>>(out, fc_b, out_size);

    for (int b0 = 0; b0 < B; b0 += Bc) {
        int bc = (Bc < B - b0) ? Bc : (B - b0);
        const float* xb = x + (size_t)b0 * CDIM * MDIM;

        unsigned short* A  = slot[0];
        unsigned short* z  = slot[1];
        unsigned short* t1 = slot[2];
        unsigned short* t2 = slot[3];

        // x -> bf16 planes in t2 (dead until GEMM2), + means + norm=0
        xcast_kernel<<<dim3(4, bc), 256, 0, stream>>>(xb, t2, means, norm);
        // covariance via MFMA (A=B=x planes), fused trace
        bgemm_kernel<<<dim3(10, bc), 256, 0, stream>>>(t2, t2, nullptr, A, 0.f, 0.f, 0, norm, means, nullptr, nullptr, b0);
        // Ahat in place + Z0
        prep_kernel<<<bc * 32, 256, 0, stream>>>(A, z, norm, bc);

        dim3 g(10, bc);
        for (int it = 0; it < 3; it++) {
            bgemm_kernel<<<g, 256, 0, stream>>>(A,  z,  nullptr, t1, 1.f,  0.f, 1, norm, means, nullptr, nullptr, b0); // t1 = Ahat@z
            bgemm_kernel<<<g, 256, 0, stream>>>(z,  t1, nullptr, t2, 1.f,  0.f, 1, norm, means, nullptr, nullptr, b0); // t2 = z@t1
            bgemm_kernel<<<g, 256, 0, stream>>>(t2, z,  z,       t1, -0.5f, 1.5f, 1, norm, means, nullptr, nullptr, b0); // z' = 1.5z-0.5 t2@z
            unsigned short* tmp = z; z = t1; t1 = tmp;
        }
        bgemm_kernel<<<g, 256, 0, stream>>>(A, z,  nullptr, t1, 1.f,  0.f, 1, norm, means, nullptr, nullptr, b0);      // Y3 = Ahat@z
        bgemm_kernel<<<g, 256, 0, stream>>>(z, t1, nullptr, t2, 1.f,  0.f, 1, norm, means, nullptr, nullptr, b0);      // P  = z@Y3
        bgemm_kernel<<<g, 256, 0, stream>>>(t1, t2, t1, nullptr, -0.5f, 1.5f, 2, norm, means, fc_w, out, b0);          // fc epilogue
    }
}